// Round 1
// baseline (655.680 us; speedup 1.0000x reference)
//
#include <hip/hip_runtime.h>
#include <cstdint>
#include <cstddef>

// Problem constants (fixed by reference)
#define NB      64      // batch
#define NBITS   4096
#define HD      64      // hidden
#define IN_DIM  4098
#define LMAXT   320
#define SEQ_STRIDE 336  // padded seq row (>= LMAX+2, mult of 16)

// Workspace layout (bytes)
static constexpr size_t STEPS_OFF = (size_t)NB * SEQ_STRIDE * 4;   // 86016
static constexpr size_t LOSS_OFF  = STEPS_OFF + NB * 4;            // 86272
static constexpr size_t OUTS_OFF  = 86528;                          // 256-aligned
// outs: NB * LMAXT * HD floats = 5.24 MB  -> total ws use ~5.33 MB

// ---------------------------------------------------------------------------
// Kernel A: per-row compaction of aug>0 positions (ascending scan == sort).
// grid <NB, 64>. Also zeroes the loss accumulator.
// ---------------------------------------------------------------------------
__global__ __launch_bounds__(64) void k_setup(
    const float* __restrict__ true_fp, const int* __restrict__ perm,
    int* __restrict__ seq, int* __restrict__ steps,
    float* __restrict__ loss_accum) {
  const int b = blockIdx.x;
  const int j = threadIdx.x;
  if (b == 0 && j == 0) *loss_accum = 0.f;
  const float* row = true_fp + (size_t)b * NBITS;
  int* srow = seq + b * SEQ_STRIDE;
  int base = 0;
  for (int c0 = 0; c0 < IN_DIM; c0 += 64) {
    const int col = c0 + j;
    bool pred = false;
    if (col < IN_DIM) {
      if (col == 0 || col == IN_DIM - 1) pred = true;
      else pred = row[perm[col - 1]] > 0.f;
    }
    const unsigned long long mask = __ballot(pred);
    const int prefix = __popcll(mask & ((1ull << j) - 1ull));
    const int idx = base + prefix;
    if (pred && idx <= LMAXT) srow[idx] = col;   // cap at LMAX+1 entries
    base += __popcll(mask);
  }
  // zero-pad the tail so later kernels never read poison
  const int cap = (base <= LMAXT + 1) ? base : (LMAXT + 1);
  for (int i = cap + j; i < SEQ_STRIDE; i += 64) srow[i] = 0;
  if (j == 0) {
    int s = base - 1;              // #nonzero targets for this row
    if (s > LMAXT) s = LMAXT;
    steps[b] = s;
  }
}

// ---------------------------------------------------------------------------
// Kernel B: GRU recurrence, one block per batch row, 192 threads (one per
// gate output g). W_hh column in VGPRs; h broadcast via LDS; early exit at
// steps[b]. Writes outs[b][t][:] (fp32).
// ---------------------------------------------------------------------------
__global__ __launch_bounds__(192) void k_gru(
    const float* __restrict__ embeds,
    const float* __restrict__ W_ih, const float* __restrict__ b_ih,
    const float* __restrict__ W_hh, const float* __restrict__ b_hh,
    const int* __restrict__ seq, const int* __restrict__ steps,
    float* __restrict__ outs) {
  const int b = blockIdx.x;
  const int g = threadIdx.x;

  __shared__ __align__(16) float hlds[HD];
  __shared__ float ghs[3 * HD];
  __shared__ float gis[3 * HD];
  __shared__ int   seqL[LMAXT + 2];

  // preload this thread's W_hh column (64 floats) into registers
  float4 wc[16];
#pragma unroll
  for (int kk = 0; kk < 16; ++kk) {
    wc[kk].x = W_hh[(4 * kk + 0) * 192 + g];
    wc[kk].y = W_hh[(4 * kk + 1) * 192 + g];
    wc[kk].z = W_hh[(4 * kk + 2) * 192 + g];
    wc[kk].w = W_hh[(4 * kk + 3) * 192 + g];
  }
  const float bh = b_hh[g];
  const float bi = b_ih[g];
  const int nst = steps[b];

  for (int i = g; i < LMAXT + 2; i += 192) seqL[i] = seq[b * SEQ_STRIDE + i];
  if (g < HD) hlds[g] = embeds[b * HD + g];
  __syncthreads();

  float gi = W_ih[(size_t)seqL[0] * 192 + g] + bi;

  for (int t = 0; t < nst; ++t) {
    // prefetch next step's input projection element (hidden under gh compute)
    const float gi_next_w = W_ih[(size_t)seqL[t + 1] * 192 + g];

    // gh[g] = b_hh[g] + sum_k h[k] * W_hh[k][g]
    const float4* h4 = (const float4*)hlds;
    float s0 = 0.f, s1 = 0.f, s2 = 0.f, s3 = 0.f;
#pragma unroll
    for (int kk = 0; kk < 16; ++kk) {
      const float4 hv = h4[kk];
      s0 = fmaf(hv.x, wc[kk].x, s0);
      s1 = fmaf(hv.y, wc[kk].y, s1);
      s2 = fmaf(hv.z, wc[kk].z, s2);
      s3 = fmaf(hv.w, wc[kk].w, s3);
    }
    const float gh = bh + ((s0 + s1) + (s2 + s3));
    const float h_old = (g < HD) ? hlds[g] : 0.f;   // read BEFORE barrier
    ghs[g] = gh;
    gis[g] = gi;
    __syncthreads();   // gh/gi visible; everyone done reading h

    if (g < HD) {
      const float r = 1.f / (1.f + __expf(-(gis[g] + ghs[g])));
      const float z = 1.f / (1.f + __expf(-(gis[HD + g] + ghs[HD + g])));
      const float nx = gis[2 * HD + g] + r * ghs[2 * HD + g];
      // safe tanh via exp of non-positive argument
      const float ax = fabsf(nx);
      const float e  = __expf(-2.f * ax);
      float th = (1.f - e) / (1.f + e);
      th = (nx < 0.f) ? -th : th;
      const float hn = (1.f - z) * th + z * h_old;
      hlds[g] = hn;
      outs[((size_t)b * LMAXT + t) * HD + g] = hn;
    }
    __syncthreads();   // new h visible for next iteration
    gi = gi_next_w + bi;
  }
}

// ---------------------------------------------------------------------------
// Kernel C: fused projection + online logsumexp + NLL.
// Tile: 32 rows (t positions) x full 4098 cols. Block 256 threads:
// rg = tid>>6 handles rows rg*8..rg*8+7, cid = tid&63 handles one col per
// 64-col chunk. W_out chunk staged in LDS; X tile staged transposed in LDS.
// grid <10, NB>.
// ---------------------------------------------------------------------------
#define XSTR 36   // XT leading stride (mult of 4 for aligned float4)
#define WSTR 65   // WS leading stride (2-way bank alias = free)

__global__ __launch_bounds__(256) void k_proj(
    const float* __restrict__ outs, const float* __restrict__ W_out,
    const float* __restrict__ b_out, const int* __restrict__ seq,
    const int* __restrict__ steps, float* __restrict__ loss_accum) {
  const int chunk = blockIdx.x;       // 0..9 (32 t-rows each)
  const int b = blockIdx.y;
  const int nst = steps[b];
  const int t0 = chunk * 32;
  if (t0 >= nst) return;
  int R = nst - t0; if (R > 32) R = 32;

  __shared__ __align__(16) float smem[64 * XSTR + 64 * WSTR];  // 25.9 KB
  float* XT = smem;                // [64][XSTR]  (k-major, transposed X)
  float* WS = smem + 64 * XSTR;    // [64][WSTR]

  const int tid = threadIdx.x;

  // stage X tile (transpose: XT[k][r] = outs[b][t0+r][k]); zero rows >= R
  {
    const int r  = tid >> 3;            // 0..31
    const int k0 = (tid & 7) * 8;       // 0,8,...,56
    if (r < R) {
      const float4* src =
          (const float4*)(outs + ((size_t)b * LMAXT + t0 + r) * HD + k0);
      const float4 v0 = src[0], v1 = src[1];
      XT[(k0 + 0) * XSTR + r] = v0.x;  XT[(k0 + 1) * XSTR + r] = v0.y;
      XT[(k0 + 2) * XSTR + r] = v0.z;  XT[(k0 + 3) * XSTR + r] = v0.w;
      XT[(k0 + 4) * XSTR + r] = v1.x;  XT[(k0 + 5) * XSTR + r] = v1.y;
      XT[(k0 + 6) * XSTR + r] = v1.z;  XT[(k0 + 7) * XSTR + r] = v1.w;
    } else {
#pragma unroll
      for (int jj = 0; jj < 8; ++jj) XT[(k0 + jj) * XSTR + r] = 0.f;
    }
  }

  const int rg  = tid >> 6;   // 0..3 -> rows rg*8 .. rg*8+7
  const int cid = tid & 63;

  float m[8], s[8];
#pragma unroll
  for (int i = 0; i < 8; ++i) { m[i] = -1e30f; s[i] = 0.f; }

  for (int cc = 0; cc < IN_DIM; cc += 64) {
    __syncthreads();   // protect WS reuse (and XT on first iteration)
    // stage W_out[:, cc:cc+64] -> WS (coalesced: 64 consecutive floats/row)
    {
      const bool cok = (cc + cid) < IN_DIM;
      for (int k = (tid >> 6); k < 64; k += 4)
        WS[k * WSTR + cid] = cok ? W_out[(size_t)k * IN_DIM + cc + cid] : 0.f;
    }
    __syncthreads();

    float acc[8];
#pragma unroll
    for (int i = 0; i < 8; ++i) acc[i] = 0.f;
#pragma unroll 16
    for (int k = 0; k < 64; ++k) {
      const float w = WS[k * WSTR + cid];
      const float4* x4 = (const float4*)(XT + k * XSTR + rg * 8);
      const float4 xa = x4[0], xb = x4[1];
      acc[0] = fmaf(xa.x, w, acc[0]);
      acc[1] = fmaf(xa.y, w, acc[1]);
      acc[2] = fmaf(xa.z, w, acc[2]);
      acc[3] = fmaf(xa.w, w, acc[3]);
      acc[4] = fmaf(xb.x, w, acc[4]);
      acc[5] = fmaf(xb.y, w, acc[5]);
      acc[6] = fmaf(xb.z, w, acc[6]);
      acc[7] = fmaf(xb.w, w, acc[7]);
    }
    const int col = cc + cid;
    if (col < IN_DIM) {
      const float bo = b_out[col];
#pragma unroll
      for (int i = 0; i < 8; ++i) {
        const float l  = acc[i] + bo;
        const float nm = fmaxf(m[i], l);
        s[i] = s[i] * __expf(m[i] - nm) + __expf(l - nm);
        m[i] = nm;
      }
    }
  }

  // target logit (recompute directly; XT still live)
  float tl = 0.f;
  if (tid < 32 && tid < R) {
    const int col = seq[b * SEQ_STRIDE + t0 + tid + 1];
    float acc = b_out[col];
#pragma unroll 8
    for (int k = 0; k < 64; ++k)
      acc = fmaf(XT[k * XSTR + tid], W_out[(size_t)k * IN_DIM + col], acc);
    tl = acc;
  }
  __syncthreads();   // done reading XT/WS -> safe to overlay

  // merge per-row (m,s) across the 64 lanes that share each row
  float* M = smem;           // [32][WSTR]
  float* S = smem + 32 * WSTR;
#pragma unroll
  for (int i = 0; i < 8; ++i) {
    const int r = rg * 8 + i;
    M[r * WSTR + cid] = m[i];
    S[r * WSTR + cid] = s[i];
  }
  __syncthreads();

  float nll = 0.f;
  if (tid < 32 && tid < R) {
    float mm = -1e30f, ss = 0.f;
#pragma unroll 8
    for (int l = 0; l < 64; ++l) {
      const float ml = M[tid * WSTR + l];
      const float sl = S[tid * WSTR + l];
      const float nm = fmaxf(mm, ml);
      ss = ss * __expf(mm - nm) + sl * __expf(ml - nm);
      mm = nm;
    }
    nll = (mm + logf(ss)) - tl;
  }
  // wave-0 reduction, one atomic per block
  if (tid < 64) {
#pragma unroll
    for (int off = 32; off > 0; off >>= 1) nll += __shfl_down(nll, off);
    if (tid == 0) atomicAdd(loss_accum, nll);
  }
}

// ---------------------------------------------------------------------------
// Kernel D: finalize (loss_sum / count). count = sum(steps) deterministically.
// ---------------------------------------------------------------------------
__global__ void k_final(const float* __restrict__ loss_accum,
                        const int* __restrict__ steps,
                        float* __restrict__ out) {
  if (threadIdx.x == 0 && blockIdx.x == 0) {
    int cnt = 0;
    for (int i = 0; i < NB; ++i) cnt += steps[i];
    out[0] = loss_accum[0] / (float)cnt;
  }
}

// ---------------------------------------------------------------------------
extern "C" void kernel_launch(void* const* d_in, const int* in_sizes, int n_in,
                              void* d_out, int out_size, void* d_ws,
                              size_t ws_size, hipStream_t stream) {
  const float* embeds  = (const float*)d_in[0];
  const float* true_fp = (const float*)d_in[1];
  // d_in[2] cand_fp, d_in[3] batch_ptr, d_in[4] labels: unused by reference math
  const int*   perm    = (const int*)d_in[5];
  const float* W_ih    = (const float*)d_in[6];
  const float* b_ih    = (const float*)d_in[7];
  const float* W_hh    = (const float*)d_in[8];
  const float* b_hh    = (const float*)d_in[9];
  const float* W_out   = (const float*)d_in[10];
  const float* b_out   = (const float*)d_in[11];

  char*  ws    = (char*)d_ws;
  int*   seq   = (int*)ws;
  int*   steps = (int*)(ws + STEPS_OFF);
  float* loss  = (float*)(ws + LOSS_OFF);
  float* outs  = (float*)(ws + OUTS_OFF);
  float* out   = (float*)d_out;

  k_setup<<<NB, 64, 0, stream>>>(true_fp, perm, seq, steps, loss);
  k_gru<<<NB, 192, 0, stream>>>(embeds, W_ih, b_ih, W_hh, b_hh, seq, steps, outs);
  k_proj<<<dim3(10, NB), 256, 0, stream>>>(outs, W_out, b_out, seq, steps, loss);
  k_final<<<1, 64, 0, stream>>>(loss, steps, out);
}

// Round 2
// 323.836 us; speedup vs baseline: 2.0247x; 2.0247x over previous
//
#include <hip/hip_runtime.h>
#include <cstdint>
#include <cstddef>

// Problem constants (fixed by reference)
#define NB      64      // batch
#define NBITS   4096
#define HD      64      // hidden
#define IN_DIM  4098
#define LMAXT   320
#define SEQ_STRIDE 336  // padded seq row (>= LMAX+2, mult of 16)
#define NTILE   257     // col tiles of 16 (4112 padded cols)

// Workspace layout (bytes), all 256-aligned
static constexpr size_t SEQ_OFF   = 0;                               // 86016
static constexpr size_t STEPS_OFF = 86016;                           // 256
static constexpr size_t LOSS_OFF  = 86272;                           // 256
static constexpr size_t XB_OFF    = 86528;                           // 64*320*64*2 = 2621440
static constexpr size_t WB_OFF    = XB_OFF + 2621440;                // 257*1024*2 = 526336
static constexpr size_t BO_OFF    = WB_OFF + 526336;                 // 4112*4

typedef __bf16 bf16x8 __attribute__((ext_vector_type(8)));
typedef float  f32x4  __attribute__((ext_vector_type(4)));

__device__ __forceinline__ unsigned short f2bf(float f) {
  unsigned u = __float_as_uint(f);
  unsigned r = u + 0x7FFFu + ((u >> 16) & 1u);   // RNE
  return (unsigned short)(r >> 16);
}
__device__ __forceinline__ float bf2f(unsigned short u) {
  return __uint_as_float((unsigned)u << 16);
}
__device__ __forceinline__ bf16x8 ldb8(const unsigned short* p) {
  return *(const bf16x8*)p;
}

// ---------------------------------------------------------------------------
// Kernel A: per-row compaction of aug>0 positions (ascending scan == sort).
// ---------------------------------------------------------------------------
__global__ __launch_bounds__(64) void k_setup(
    const float* __restrict__ true_fp, const int* __restrict__ perm,
    int* __restrict__ seq, int* __restrict__ steps,
    float* __restrict__ loss_accum) {
  const int b = blockIdx.x;
  const int j = threadIdx.x;
  if (b == 0 && j == 0) *loss_accum = 0.f;
  const float* row = true_fp + (size_t)b * NBITS;
  int* srow = seq + b * SEQ_STRIDE;
  int base = 0;
  for (int c0 = 0; c0 < IN_DIM; c0 += 64) {
    const int col = c0 + j;
    bool pred = false;
    if (col < IN_DIM) {
      if (col == 0 || col == IN_DIM - 1) pred = true;
      else pred = row[perm[col - 1]] > 0.f;
    }
    const unsigned long long mask = __ballot(pred);
    const int prefix = __popcll(mask & ((1ull << j) - 1ull));
    const int idx = base + prefix;
    if (pred && idx <= LMAXT) srow[idx] = col;   // keep LMAX+1 entries
    base += __popcll(mask);
  }
  const int cap = (base <= LMAXT + 1) ? base : (LMAXT + 1);
  for (int i = cap + j; i < SEQ_STRIDE; i += 64) srow[i] = 0;
  if (j == 0) {
    int s = base - 1;
    if (s > LMAXT) s = LMAXT;
    steps[b] = s;
  }
}

// ---------------------------------------------------------------------------
// Kernel A2: build bf16 fragment-major W tiles + shifted bias.
// Wb[c][m][k] (c=col tile, m=col within tile, k=hidden) so a B-fragment lane
// reads its 8 k-values as ONE 16B load. bo_pad[col] = b_out[col]-30 (pad -1e30).
// ---------------------------------------------------------------------------
__global__ __launch_bounds__(256) void k_prep(
    const float* __restrict__ W_out, const float* __restrict__ b_out,
    unsigned short* __restrict__ Wb, float* __restrict__ bo_pad) {
  const int c = blockIdx.x;            // 0..256
  const int t = threadIdx.x;
  for (int i = t; i < 1024; i += 256) {
    const int m = i >> 6, k = i & 63;
    const int col = c * 16 + m;
    const float v = (col < IN_DIM) ? W_out[(size_t)k * IN_DIM + col] : 0.f;
    Wb[c * 1024 + i] = f2bf(v);
  }
  if (t < 16) {
    const int col = c * 16 + t;
    bo_pad[c * 16 + t] = (col < IN_DIM) ? (b_out[col] - 30.f) : -1e30f;
  }
}

// ---------------------------------------------------------------------------
// Kernel B: GRU recurrence (unchanged structure), now emitting bf16 Xb rows
// and zero-filling rows t in [nst, LMAXT) so k_proj never sees ws poison.
// ---------------------------------------------------------------------------
__global__ __launch_bounds__(192) void k_gru(
    const float* __restrict__ embeds,
    const float* __restrict__ W_ih, const float* __restrict__ b_ih,
    const float* __restrict__ W_hh, const float* __restrict__ b_hh,
    const int* __restrict__ seq, const int* __restrict__ steps,
    unsigned short* __restrict__ Xb) {
  const int b = blockIdx.x;
  const int g = threadIdx.x;

  __shared__ __align__(16) float hlds[HD];
  __shared__ float ghs[3 * HD];
  __shared__ float gis[3 * HD];
  __shared__ int   seqL[LMAXT + 2];

  float4 wc[16];
#pragma unroll
  for (int kk = 0; kk < 16; ++kk) {
    wc[kk].x = W_hh[(4 * kk + 0) * 192 + g];
    wc[kk].y = W_hh[(4 * kk + 1) * 192 + g];
    wc[kk].z = W_hh[(4 * kk + 2) * 192 + g];
    wc[kk].w = W_hh[(4 * kk + 3) * 192 + g];
  }
  const float bh = b_hh[g];
  const float bi = b_ih[g];
  const int nst = steps[b];

  for (int i = g; i < LMAXT + 2; i += 192) seqL[i] = seq[b * SEQ_STRIDE + i];
  if (g < HD) hlds[g] = embeds[b * HD + g];
  __syncthreads();

  float gi = W_ih[(size_t)seqL[0] * 192 + g] + bi;

  for (int t = 0; t < nst; ++t) {
    const float gi_next_w = W_ih[(size_t)seqL[t + 1] * 192 + g];

    const float4* h4 = (const float4*)hlds;
    float s0 = 0.f, s1 = 0.f, s2 = 0.f, s3 = 0.f;
#pragma unroll
    for (int kk = 0; kk < 16; ++kk) {
      const float4 hv = h4[kk];
      s0 = fmaf(hv.x, wc[kk].x, s0);
      s1 = fmaf(hv.y, wc[kk].y, s1);
      s2 = fmaf(hv.z, wc[kk].z, s2);
      s3 = fmaf(hv.w, wc[kk].w, s3);
    }
    const float gh = bh + ((s0 + s1) + (s2 + s3));
    const float h_old = (g < HD) ? hlds[g] : 0.f;
    ghs[g] = gh;
    gis[g] = gi;
    __syncthreads();

    if (g < HD) {
      const float r = 1.f / (1.f + __expf(-(gis[g] + ghs[g])));
      const float z = 1.f / (1.f + __expf(-(gis[HD + g] + ghs[HD + g])));
      const float nx = gis[2 * HD + g] + r * ghs[2 * HD + g];
      const float ax = fabsf(nx);
      const float e  = __expf(-2.f * ax);
      float th = (1.f - e) / (1.f + e);
      th = (nx < 0.f) ? -th : th;
      const float hn = (1.f - z) * th + z * h_old;
      hlds[g] = hn;
      Xb[((size_t)b * LMAXT + t) * HD + g] = f2bf(hn);
    }
    __syncthreads();
    gi = gi_next_w + bi;
  }
  // zero-fill padded rows (ws is poisoned 0xAA before every call)
  for (int i = nst * HD + g; i < LMAXT * HD; i += 192)
    Xb[(size_t)b * (LMAXT * HD) + i] = 0;
}

// ---------------------------------------------------------------------------
// Kernel C: MFMA bf16 fused projection + logsumexp + NLL.
// One wave = 32 rows (two 16x16x32 row-tiles) x all 4112 cols. A-frags live
// in VGPRs for the whole kernel; B read via coalesced 16B global loads from
// Wb; no max tracking (|logit| < 29 => exp(l-30) is overflow/underflow safe).
// Grid: 160 blocks x 256 threads = 640 waves.
// ---------------------------------------------------------------------------
__global__ __launch_bounds__(256) void k_proj(
    const unsigned short* __restrict__ Xb,
    const unsigned short* __restrict__ Wb,
    const float* __restrict__ bo_pad,
    const int* __restrict__ seq, const int* __restrict__ steps,
    const float* __restrict__ b_out,
    float* __restrict__ loss_accum) {
  const int wv = threadIdx.x >> 6;
  const int l  = threadIdx.x & 63;
  const int w  = blockIdx.x * 4 + wv;      // 0..639
  const int b  = w / 10;
  const int t0 = (w % 10) * 32;
  const int nst = steps[b];

  __shared__ float srow[4][32];

  float nll = 0.f;
  if (t0 < nst) {
    const int lm = l & 15;
    const int q  = l >> 4;

    // A fragments: rows t0+lm (tile0) and t0+16+lm (tile1), k = q*8 + j (+32)
    const unsigned short* xp0 = Xb + ((size_t)b * LMAXT + t0 + lm) * HD + q * 8;
    const bf16x8 a00 = ldb8(xp0);
    const bf16x8 a01 = ldb8(xp0 + 32);
    const bf16x8 a10 = ldb8(xp0 + 16 * HD);
    const bf16x8 a11 = ldb8(xp0 + 16 * HD + 32);

    float s[8];
#pragma unroll
    for (int i = 0; i < 8; ++i) s[i] = 0.f;

    const unsigned short* wp = Wb + lm * 64 + q * 8;
    const float* bop = bo_pad + lm;

    bf16x8 b0 = ldb8(wp);
    bf16x8 b1 = ldb8(wp + 32);
    float  bo = bop[0];
    for (int ct = 0; ct < NTILE; ++ct) {
      bf16x8 nb0, nb1; float nbo;
      if (ct + 1 < NTILE) {
        const unsigned short* wpn = wp + (ct + 1) * 1024;
        nb0 = ldb8(wpn);
        nb1 = ldb8(wpn + 32);
        nbo = bop[(ct + 1) * 16];
      }
      f32x4 acc0 = {0.f, 0.f, 0.f, 0.f};
      f32x4 acc1 = {0.f, 0.f, 0.f, 0.f};
      acc0 = __builtin_amdgcn_mfma_f32_16x16x32_bf16(a00, b0, acc0, 0, 0, 0);
      acc0 = __builtin_amdgcn_mfma_f32_16x16x32_bf16(a01, b1, acc0, 0, 0, 0);
      acc1 = __builtin_amdgcn_mfma_f32_16x16x32_bf16(a10, b0, acc1, 0, 0, 0);
      acc1 = __builtin_amdgcn_mfma_f32_16x16x32_bf16(a11, b1, acc1, 0, 0, 0);
#pragma unroll
      for (int i = 0; i < 4; ++i) {
        s[i]     += __expf(acc0[i] + bo);   // exp(logit - 30), no overflow
        s[4 + i] += __expf(acc1[i] + bo);
      }
      if (ct + 1 < NTILE) { b0 = nb0; b1 = nb1; bo = nbo; }
    }

    // reduce s across the 16 lanes sharing each row (cols are lane-split)
#pragma unroll
    for (int m = 1; m < 16; m <<= 1) {
#pragma unroll
      for (int i = 0; i < 8; ++i) s[i] += __shfl_xor(s[i], m, 64);
    }
    // D-layout: lane holds rows q*4+i (tile0) / 16+q*4+i (tile1)
    if (lm == 0) {
#pragma unroll
      for (int i = 0; i < 4; ++i) {
        srow[wv][q * 4 + i]      = s[i];
        srow[wv][16 + q * 4 + i] = s[4 + i];
      }
    }
    __threadfence_block();   // wave-internal LDS write->read ordering

    if (l < 32) {
      const int t = t0 + l;
      if (t < nst) {
        const float ssum = srow[wv][l];
        const int col = seq[b * SEQ_STRIDE + t + 1];
        // target logit from the SAME bf16 operands (consistent cancellation)
        const unsigned short* xr = Xb + ((size_t)b * LMAXT + t) * HD;
        const unsigned short* wc = Wb + (size_t)(col >> 4) * 1024 + (col & 15) * 64;
        float tl = b_out[col];
#pragma unroll 16
        for (int k = 0; k < 64; ++k)
          tl = fmaf(bf2f(xr[k]), bf2f(wc[k]), tl);
        nll = (30.f + __logf(ssum)) - tl;
      }
    }
  }
#pragma unroll
  for (int off = 32; off; off >>= 1) nll += __shfl_down(nll, off, 64);
  if (l == 0) atomicAdd(loss_accum, nll);
}

// ---------------------------------------------------------------------------
// Kernel D: finalize (loss_sum / count).
// ---------------------------------------------------------------------------
__global__ void k_final(const float* __restrict__ loss_accum,
                        const int* __restrict__ steps,
                        float* __restrict__ out) {
  if (threadIdx.x == 0 && blockIdx.x == 0) {
    int cnt = 0;
    for (int i = 0; i < NB; ++i) cnt += steps[i];
    out[0] = loss_accum[0] / (float)cnt;
  }
}

// ---------------------------------------------------------------------------
extern "C" void kernel_launch(void* const* d_in, const int* in_sizes, int n_in,
                              void* d_out, int out_size, void* d_ws,
                              size_t ws_size, hipStream_t stream) {
  const float* embeds  = (const float*)d_in[0];
  const float* true_fp = (const float*)d_in[1];
  const int*   perm    = (const int*)d_in[5];
  const float* W_ih    = (const float*)d_in[6];
  const float* b_ih    = (const float*)d_in[7];
  const float* W_hh    = (const float*)d_in[8];
  const float* b_hh    = (const float*)d_in[9];
  const float* W_out   = (const float*)d_in[10];
  const float* b_out   = (const float*)d_in[11];

  char*  ws     = (char*)d_ws;
  int*   seq    = (int*)(ws + SEQ_OFF);
  int*   steps  = (int*)(ws + STEPS_OFF);
  float* loss   = (float*)(ws + LOSS_OFF);
  unsigned short* Xb = (unsigned short*)(ws + XB_OFF);
  unsigned short* Wb = (unsigned short*)(ws + WB_OFF);
  float* bo_pad = (float*)(ws + BO_OFF);
  float* out    = (float*)d_out;

  k_setup<<<NB, 64, 0, stream>>>(true_fp, perm, seq, steps, loss);
  k_prep<<<NTILE, 256, 0, stream>>>(W_out, b_out, Wb, bo_pad);
  k_gru<<<NB, 192, 0, stream>>>(embeds, W_ih, b_ih, W_hh, b_hh, seq, steps, Xb);
  k_proj<<<160, 256, 0, stream>>>(Xb, Wb, bo_pad, seq, steps, b_out, loss);
  k_final<<<1, 64, 0, stream>>>(loss, steps, out);
}